// Round 7
// baseline (6190.381 us; speedup 1.0000x reference)
//
#include <hip/hip_runtime.h>
#include <stdint.h>
#include <stddef.h>

#define TT   128
#define BB   1024
#define INN  75
#define HH   128
#define KXP  96
#define OUTN 256
#define DECN 9600
#define NBLK 32
#define NTHR 512
#define EPSB 1e-5f

typedef short v8s __attribute__((ext_vector_type(8)));   // 8 bf16 (4 VGPR) MFMA frag
typedef float v4f __attribute__((ext_vector_type(4)));   // 4 fp32 acc frag
typedef unsigned short ush;
typedef unsigned int   u32;
typedef unsigned long long u64;

// ---- static device workspace (fully rewritten every launch) ----
__device__ __align__(256) ush g_xpad[(size_t)TT * BB * KXP];   // x padded to K=96, [t][b][k] bf16
__device__ __align__(256) u64 g_h0s[(size_t)TT * BB * 32];     // h0 stream [t][row][128 bf16] as u64
__device__ __align__(256) u64 g_h1s[(size_t)TT * BB * 32];     // h1 stream
__device__ __align__(256) float g_c0[HH * BB];                 // c-state layer0 [unit][row] fp32
__device__ __align__(256) float g_c1[HH * BB];                 // c-state layer1
// weights [m][k] bf16, m permuted: origcol(m) = (m&3)*128 + (m>>4)*4 + ((m>>2)&3)
__device__ __align__(256) ush g_wtih0[512 * KXP];
__device__ __align__(256) ush g_wthh0[512 * HH];
__device__ __align__(256) ush g_wtih1[512 * HH];
__device__ __align__(256) ush g_wthh1[512 * HH];
__device__ __align__(256) ush g_fcwt[OUTN * HH];               // fc_w^T [col][k]
__device__ __align__(256) ush g_decwt[(size_t)DECN * OUTN];    // dec_w^T [col][k]
__device__ __align__(256) ush g_emb[BB * OUTN];                // fc output bf16

// ---- helpers ----
__device__ __forceinline__ ush f2bf(float f) {
  u32 u = __float_as_uint(f);
  u32 r = (u + 0x7FFFu + ((u >> 16) & 1u)) >> 16;   // RNE
  return (ush)r;
}
__device__ __forceinline__ float bf2f(ush u) { return __uint_as_float(((u32)u) << 16); }
__device__ __forceinline__ float sigf(float x)  { return 1.f / (1.f + __expf(-x)); }
__device__ __forceinline__ float tanhf_(float x){ float e = __expf(2.f * x); return 1.f - 2.f / (e + 1.f); }
__device__ __forceinline__ v8s ld8(const ush* p) { return *reinterpret_cast<const v8s*>(p); }
__device__ __forceinline__ int origcol(int m) { return (m & 3) * 128 + (m >> 4) * 4 + ((m >> 2) & 3); }

// ---- prep kernels ----
__global__ void kpackx(const float* __restrict__ seq) {
  int idx = blockIdx.x * 256 + threadIdx.x;   // < TT*BB*KXP
  int kk = idx % KXP; int rest = idx / KXP;
  int b = rest % BB;  int t = rest / BB;
  float v = (kk < INN) ? seq[((size_t)b * TT + t) * INN + kk] : 0.f;
  g_xpad[idx] = f2bf(v);
}

__global__ void kpackw(const float* __restrict__ Wih0, const float* __restrict__ Whh0,
                       const float* __restrict__ Wih1, const float* __restrict__ Whh1,
                       const float* __restrict__ fcw,  const float* __restrict__ decw) {
  int idx = blockIdx.x * 256 + threadIdx.x;   // grid 10688
  if (idx < 49152) {                          // wtih0: [m][96]
    int m = idx / KXP, k = idx % KXP;
    g_wtih0[idx] = f2bf((k < INN) ? Wih0[k * 512 + origcol(m)] : 0.f);
  } else if (idx < 114688) {
    int j = idx - 49152; int m = j / HH, k = j % HH;
    g_wthh0[j] = f2bf(Whh0[k * 512 + origcol(m)]);
  } else if (idx < 180224) {
    int j = idx - 114688; int m = j / HH, k = j % HH;
    g_wtih1[j] = f2bf(Wih1[k * 512 + origcol(m)]);
  } else if (idx < 245760) {
    int j = idx - 180224; int m = j / HH, k = j % HH;
    g_wthh1[j] = f2bf(Whh1[k * 512 + origcol(m)]);
  } else if (idx < 278528) {                  // fcwt [c][128]
    int j = idx - 245760; int c = j / HH, k = j % HH;
    g_fcwt[j] = f2bf(fcw[k * OUTN + c]);
  } else {                                    // decwt [c][256], coalesced reads
    int j = idx - 278528; int n = j % DECN, k = j / DECN;
    g_decwt[(size_t)n * OUTN + k] = f2bf(decw[(size_t)k * DECN + n]);
  }
}

// ---- per-step kernel: 32 blocks x 512 thr (8 waves). One launch per time step s.
// Column partition: block owns 4 units (16 gate cols, gate-minor) for BOTH layers
// (layer1 skewed by 1: this launch runs L0 step s and L1 step s-1).
// Transposed MFMA (A=W^T, B=rows): lane holds row=lm, unit=lq, gates f,i,o,g in the
// 4 C-regs -> in-register pointwise; both BN stat reductions block-local.
// Cross-step visibility via kernel boundaries (plain loads/stores, no atomics).
__global__ __launch_bounds__(NTHR, 1) void kstep(
    int s,
    const float* __restrict__ gih0, const float* __restrict__ bih0,
    const float* __restrict__ b0,
    const float* __restrict__ ghh0, const float* __restrict__ bhh0,
    const float* __restrict__ gc0,  const float* __restrict__ bc0,
    const float* __restrict__ gih1, const float* __restrict__ bih1,
    const float* __restrict__ ghh1, const float* __restrict__ bhh1,
    const float* __restrict__ b1,   const float* __restrict__ gc1,
    const float* __restrict__ bc1) {
  const int tid = threadIdx.x;
  const int wv = tid >> 6, l = tid & 63;
  const int lm = l & 15, lq = l >> 4;
  const int nb = blockIdx.x;
  const int R0 = wv * 128;

  __shared__ float sparam[16][10];
  __shared__ float scparam[4][4];
  __shared__ float sred[8][16][8];
  __shared__ float scoef[16][6];
  __shared__ float scred[8][4][4];
  __shared__ float sccoef[4][4];

  if (tid < 16) {
    int oc = origcol(nb * 16 + tid);
    sparam[tid][0] = gih0[oc]; sparam[tid][1] = bih0[oc]; sparam[tid][2] = b0[oc];
    sparam[tid][3] = ghh0[oc]; sparam[tid][4] = bhh0[oc];
    sparam[tid][5] = gih1[oc]; sparam[tid][6] = bih1[oc];
    sparam[tid][7] = ghh1[oc]; sparam[tid][8] = bhh1[oc]; sparam[tid][9] = b1[oc];
  }
  if (tid >= 16 && tid < 20) {
    int u = nb * 4 + (tid - 16);
    scparam[tid - 16][0] = gc0[u]; scparam[tid - 16][1] = bc0[u];
    scparam[tid - 16][2] = gc1[u]; scparam[tid - 16][3] = bc1[u];
  }
  __syncthreads();

  const bool aL0 = (s < TT), aL1 = (s >= 1), ah0 = (s >= 1), ah1 = (s >= 2);
  const ush* const h0r = reinterpret_cast<const ush*>(g_h0s);
  const ush* const h1r = reinterpret_cast<const ush*>(g_h1s);
  const int u = nb * 4 + lq;   // this lane's unit

  // ---- c-state load (fp32, coalesced within lm-groups) ----
  float c0st[8], c1st[8], so0[8], so1[8];
#pragma unroll
  for (int mt = 0; mt < 8; ++mt) {
    c0st[mt] = (aL0 && s > 0) ? g_c0[u * BB + R0 + mt * 16 + lm] : 0.f;
    c1st[mt] = (ah1)          ? g_c1[u * BB + R0 + mt * 16 + lm] : 0.f;
    so0[mt] = 0.f; so1[mt] = 0.f;
  }

  // weight A-frags
  v8s afx[3], af0[4], af1[4], af2[4];
#pragma unroll
  for (int ks = 0; ks < 3; ++ks)
    afx[ks] = ld8(&g_wtih0[(nb * 16 + lm) * KXP + ks * 32 + lq * 8]);
#pragma unroll
  for (int ks = 0; ks < 4; ++ks) {
    af0[ks] = ld8(&g_wthh0[(nb * 16 + lm) * HH + ks * 32 + lq * 8]);
    af1[ks] = ld8(&g_wtih1[(nb * 16 + lm) * HH + ks * 32 + lq * 8]);
    af2[ks] = ld8(&g_wthh1[(nb * 16 + lm) * HH + ks * 32 + lq * 8]);
  }

  const v4f vz = {0.f, 0.f, 0.f, 0.f};
  v4f Pi0[8], P0[8], P1[8], P2[8];
#pragma unroll
  for (int mt = 0; mt < 8; ++mt) { Pi0[mt] = vz; P0[mt] = vz; P1[mt] = vz; P2[mt] = vz; }

  // ---- GEMMs (B operand = rows of x / h, same frag pattern) ----
  if (aL0) {
#pragma unroll
    for (int mt = 0; mt < 8; ++mt) {
      const ush* xp = g_xpad + ((size_t)s * BB + R0 + mt * 16 + lm) * KXP + lq * 8;
#pragma unroll
      for (int ks = 0; ks < 3; ++ks)
        Pi0[mt] = __builtin_amdgcn_mfma_f32_16x16x32_bf16(afx[ks], ld8(xp + ks * 32), Pi0[mt], 0, 0, 0);
    }
  }
  if (ah0) {
#pragma unroll
    for (int mt = 0; mt < 8; ++mt) {
      const ush* hp = h0r + ((size_t)(s - 1) * BB + R0 + mt * 16 + lm) * HH + lq * 8;
#pragma unroll
      for (int ks = 0; ks < 4; ++ks) {
        v8s b = ld8(hp + ks * 32);
        P0[mt] = __builtin_amdgcn_mfma_f32_16x16x32_bf16(af0[ks], b, P0[mt], 0, 0, 0);
        P1[mt] = __builtin_amdgcn_mfma_f32_16x16x32_bf16(af1[ks], b, P1[mt], 0, 0, 0);
      }
    }
  }
  if (ah1) {
#pragma unroll
    for (int mt = 0; mt < 8; ++mt) {
      const ush* hp = h1r + ((size_t)(s - 2) * BB + R0 + mt * 16 + lm) * HH + lq * 8;
#pragma unroll
      for (int ks = 0; ks < 4; ++ks)
        P2[mt] = __builtin_amdgcn_mfma_f32_16x16x32_bf16(af2[ks], ld8(hp + ks * 32), P2[mt], 0, 0, 0);
    }
  }

  // ---- gate stats (block-local): 4 streams, per-col S,Q over rows ----
  float S[4][4], Q[4][4];
#pragma unroll
  for (int st = 0; st < 4; ++st)
#pragma unroll
    for (int r = 0; r < 4; ++r) { S[st][r] = 0.f; Q[st][r] = 0.f; }
#pragma unroll
  for (int mt = 0; mt < 8; ++mt)
#pragma unroll
    for (int r = 0; r < 4; ++r) {
      float a = Pi0[mt][r]; S[0][r] += a; Q[0][r] += a * a;
      float b = P0[mt][r];  S[1][r] += b; Q[1][r] += b * b;
      float c = P1[mt][r];  S[2][r] += c; Q[2][r] += c * c;
      float d = P2[mt][r];  S[3][r] += d; Q[3][r] += d * d;
    }
#pragma unroll
  for (int st = 0; st < 4; ++st)
#pragma unroll
    for (int r = 0; r < 4; ++r) {
      float s_ = S[st][r], q_ = Q[st][r];
#pragma unroll
      for (int off = 1; off < 16; off <<= 1) { s_ += __shfl_xor(s_, off); q_ += __shfl_xor(q_, off); }
      S[st][r] = s_; Q[st][r] = q_;
    }
  if (lm == 0)
#pragma unroll
    for (int r = 0; r < 4; ++r)
#pragma unroll
      for (int st = 0; st < 4; ++st) {
        sred[wv][lq * 4 + r][st * 2]     = S[st][r];
        sred[wv][lq * 4 + r][st * 2 + 1] = Q[st][r];
      }
  __syncthreads();
  if (tid < 16) {
    float t8[8] = {0.f, 0.f, 0.f, 0.f, 0.f, 0.f, 0.f, 0.f};
#pragma unroll
    for (int w8 = 0; w8 < 8; ++w8)
#pragma unroll
      for (int j = 0; j < 8; ++j) t8[j] += sred[w8][tid][j];
    float mi0 = t8[0] * (1.f / BB), vi0 = t8[1] * (1.f / BB) - mi0 * mi0;
    float Ai0 = sparam[tid][0] * rsqrtf(vi0 + EPSB);
    float mh0 = t8[2] * (1.f / BB), vh0 = t8[3] * (1.f / BB) - mh0 * mh0;
    float Ah0 = sparam[tid][3] * rsqrtf(vh0 + EPSB);
    float D0v = sparam[tid][1] - Ai0 * mi0 + sparam[tid][4] - Ah0 * mh0 + sparam[tid][2];
    float mi1 = t8[4] * (1.f / BB), vi1 = t8[5] * (1.f / BB) - mi1 * mi1;
    float Ai1 = sparam[tid][5] * rsqrtf(vi1 + EPSB);
    float mh1 = t8[6] * (1.f / BB), vh1 = t8[7] * (1.f / BB) - mh1 * mh1;
    float Ah1 = sparam[tid][7] * rsqrtf(vh1 + EPSB);
    float D1v = sparam[tid][6] - Ai1 * mi1 + sparam[tid][8] - Ah1 * mh1 + sparam[tid][9];
    scoef[tid][0] = Ai0; scoef[tid][1] = Ah0; scoef[tid][2] = D0v;
    scoef[tid][3] = Ai1; scoef[tid][4] = Ah1; scoef[tid][5] = D1v;
  }
  __syncthreads();
  float AI0[4], AH0[4], D0[4], AI1[4], AH1[4], D1[4];
#pragma unroll
  for (int r = 0; r < 4; ++r) {
    AI0[r] = scoef[lq * 4 + r][0]; AH0[r] = scoef[lq * 4 + r][1]; D0[r] = scoef[lq * 4 + r][2];
    AI1[r] = scoef[lq * 4 + r][3]; AH1[r] = scoef[lq * 4 + r][4]; D1[r] = scoef[lq * 4 + r][5];
  }

  // ---- pointwise, fully in-register (reg r = gate f,i,o,g of unit lq) ----
  float cS0 = 0.f, cQ0 = 0.f, cS1 = 0.f, cQ1 = 0.f;
#pragma unroll
  for (int mt = 0; mt < 8; ++mt) {
    if (aL0) {
      float gf = AI0[0] * Pi0[mt][0] + AH0[0] * P0[mt][0] + D0[0];
      float gi = AI0[1] * Pi0[mt][1] + AH0[1] * P0[mt][1] + D0[1];
      float go = AI0[2] * Pi0[mt][2] + AH0[2] * P0[mt][2] + D0[2];
      float gg = AI0[3] * Pi0[mt][3] + AH0[3] * P0[mt][3] + D0[3];
      float c1 = sigf(gf) * c0st[mt] + sigf(gi) * tanhf_(gg);
      c0st[mt] = c1; so0[mt] = sigf(go);
      cS0 += c1; cQ0 += c1 * c1;
    }
    if (aL1) {
      float gf = AI1[0] * P1[mt][0] + AH1[0] * P2[mt][0] + D1[0];
      float gi = AI1[1] * P1[mt][1] + AH1[1] * P2[mt][1] + D1[1];
      float go = AI1[2] * P1[mt][2] + AH1[2] * P2[mt][2] + D1[2];
      float gg = AI1[3] * P1[mt][3] + AH1[3] * P2[mt][3] + D1[3];
      float c1 = sigf(gf) * c1st[mt] + sigf(gi) * tanhf_(gg);
      c1st[mt] = c1; so1[mt] = sigf(go);
      cS1 += c1; cQ1 += c1 * c1;
    }
  }
  // persist c-state
#pragma unroll
  for (int mt = 0; mt < 8; ++mt) {
    if (aL0) g_c0[u * BB + R0 + mt * 16 + lm] = c0st[mt];
    if (aL1) g_c1[u * BB + R0 + mt * 16 + lm] = c1st[mt];
  }

  // ---- c-BN stats (block-local) ----
#pragma unroll
  for (int off = 1; off < 16; off <<= 1) {
    cS0 += __shfl_xor(cS0, off); cQ0 += __shfl_xor(cQ0, off);
    cS1 += __shfl_xor(cS1, off); cQ1 += __shfl_xor(cQ1, off);
  }
  if (lm == 0) {
    scred[wv][lq][0] = cS0; scred[wv][lq][1] = cQ0;
    scred[wv][lq][2] = cS1; scred[wv][lq][3] = cQ1;
  }
  __syncthreads();
  if (tid < 4) {
    float t4[4] = {0.f, 0.f, 0.f, 0.f};
#pragma unroll
    for (int w8 = 0; w8 < 8; ++w8)
#pragma unroll
      for (int j = 0; j < 4; ++j) t4[j] += scred[w8][tid][j];
    float m0 = t4[0] * (1.f / BB), v0 = t4[1] * (1.f / BB) - m0 * m0;
    float ac0 = scparam[tid][0] * rsqrtf(v0 + EPSB);
    float m1 = t4[2] * (1.f / BB), v1 = t4[3] * (1.f / BB) - m1 * m1;
    float ac1 = scparam[tid][2] * rsqrtf(v1 + EPSB);
    sccoef[tid][0] = ac0; sccoef[tid][1] = scparam[tid][1] - ac0 * m0;
    sccoef[tid][2] = ac1; sccoef[tid][3] = scparam[tid][3] - ac1 * m1;
  }
  __syncthreads();
  const float ac0 = sccoef[lq][0], dc0 = sccoef[lq][1];
  const float ac1 = sccoef[lq][2], dc1 = sccoef[lq][3];

  // ---- h outputs: pack 4 units via shfl, plain u64 store ----
  if (aL0) {
#pragma unroll
    for (int mt = 0; mt < 8; ++mt) {
      u32 v = (u32)f2bf(so0[mt] * tanhf_(ac0 * c0st[mt] + dc0));
      u32 a = v | (__shfl_xor(v, 16) << 16);   // valid on even lq
      u32 b = __shfl_xor(a, 32);               // lq0 <- (u2,u3)
      if (l < 16)
        g_h0s[((size_t)s * BB + R0 + mt * 16 + lm) * 32 + nb] = (u64)a | ((u64)b << 32);
    }
  }
  if (aL1) {
#pragma unroll
    for (int mt = 0; mt < 8; ++mt) {
      u32 v = (u32)f2bf(so1[mt] * tanhf_(ac1 * c1st[mt] + dc1));
      u32 a = v | (__shfl_xor(v, 16) << 16);
      u32 b = __shfl_xor(a, 32);
      if (l < 16)
        g_h1s[((size_t)(s - 1) * BB + R0 + mt * 16 + lm) * 32 + nb] = (u64)a | ((u64)b << 32);
    }
  }
}

// ---- epilogue: emb = h1(T-1) @ fc_w + fc_b (bf16 out) ----
__global__ __launch_bounds__(256) void kfc(const float* __restrict__ fcb) {
  const int tid = threadIdx.x, w = tid >> 6, l = tid & 63;
  const int lm = l & 15, lq = l >> 4;
  const int col = blockIdx.x * 16 + lm;   // grid 16
  const ush* hsrc = reinterpret_cast<const ush*>(g_h1s) + (size_t)(TT - 1) * BB * HH;
  v8s bf[4];
#pragma unroll
  for (int ks = 0; ks < 4; ++ks) bf[ks] = ld8(&g_fcwt[col * HH + ks * 32 + lq * 8]);
  const float bias = fcb[col];
  const v4f vz = {0.f, 0.f, 0.f, 0.f};
#pragma unroll
  for (int mt = 0; mt < 16; ++mt) {
    const int rowa = w * 256 + mt * 16 + lm;
    const ush* ap = hsrc + (size_t)rowa * HH + lq * 8;
    v4f acc = vz;
#pragma unroll
    for (int ks = 0; ks < 4; ++ks)
      acc = __builtin_amdgcn_mfma_f32_16x16x32_bf16(ld8(ap + ks * 32), bf[ks], acc, 0, 0, 0);
#pragma unroll
    for (int r = 0; r < 4; ++r) {
      int row = w * 256 + mt * 16 + lq * 4 + r;
      g_emb[row * OUTN + col] = f2bf(acc[r] + bias);
    }
  }
}

// ---- epilogue: out = emb @ dec_w + dec_b (fp32 out) ----
__global__ __launch_bounds__(256) void kdec(const float* __restrict__ decb, float* __restrict__ out) {
  const int tid = threadIdx.x, w = tid >> 6, l = tid & 63;
  const int lm = l & 15, lq = l >> 4;
  const int col = blockIdx.x * 16 + lm;   // grid 600
  v8s bf[8];
#pragma unroll
  for (int ks = 0; ks < 8; ++ks) bf[ks] = ld8(&g_decwt[(size_t)col * OUTN + ks * 32 + lq * 8]);
  const float bias = decb[col];
  const v4f vz = {0.f, 0.f, 0.f, 0.f};
#pragma unroll
  for (int mt = 0; mt < 16; ++mt) {
    const int rowa = w * 256 + mt * 16 + lm;
    const ush* ap = g_emb + (size_t)rowa * OUTN + lq * 8;
    v4f acc = vz;
#pragma unroll
    for (int ks = 0; ks < 8; ++ks)
      acc = __builtin_amdgcn_mfma_f32_16x16x32_bf16(ld8(ap + ks * 32), bf[ks], acc, 0, 0, 0);
#pragma unroll
    for (int r = 0; r < 4; ++r) {
      int row = w * 256 + mt * 16 + lq * 4 + r;
      out[(size_t)row * DECN + col] = acc[r] + bias;
    }
  }
}

extern "C" void kernel_launch(void* const* d_in, const int* in_sizes, int n_in,
                              void* d_out, int out_size, void* d_ws, size_t ws_size,
                              hipStream_t stream) {
  const float* seq  = (const float*)d_in[0];
  const float* Wih0 = (const float*)d_in[1];
  const float* Whh0 = (const float*)d_in[2];
  const float* b0   = (const float*)d_in[3];
  const float* gih0 = (const float*)d_in[4];
  const float* bih0 = (const float*)d_in[5];
  const float* ghh0 = (const float*)d_in[6];
  const float* bhh0 = (const float*)d_in[7];
  const float* gc0  = (const float*)d_in[8];
  const float* bc0  = (const float*)d_in[9];
  const float* Wih1 = (const float*)d_in[10];
  const float* Whh1 = (const float*)d_in[11];
  const float* b1   = (const float*)d_in[12];
  const float* gih1 = (const float*)d_in[13];
  const float* bih1 = (const float*)d_in[14];
  const float* ghh1 = (const float*)d_in[15];
  const float* bhh1 = (const float*)d_in[16];
  const float* gc1  = (const float*)d_in[17];
  const float* bc1  = (const float*)d_in[18];
  const float* fcw  = (const float*)d_in[19];
  const float* fcb  = (const float*)d_in[20];
  const float* decw = (const float*)d_in[21];
  const float* decb = (const float*)d_in[22];
  float* out = (float*)d_out;
  (void)in_sizes; (void)n_in; (void)out_size; (void)d_ws; (void)ws_size;

  kpackx<<<dim3((TT * BB * KXP) / 256), dim3(256), 0, stream>>>(seq);
  kpackw<<<dim3(10688), dim3(256), 0, stream>>>(Wih0, Whh0, Wih1, Whh1, fcw, decw);
  for (int s = 0; s <= TT; ++s)
    kstep<<<dim3(NBLK), dim3(NTHR), 0, stream>>>(s, gih0, bih0, b0, ghh0, bhh0, gc0, bc0,
                                                 gih1, bih1, ghh1, bhh1, b1, gc1, bc1);
  kfc<<<dim3(16), dim3(256), 0, stream>>>(fcb);
  kdec<<<dim3(600), dim3(256), 0, stream>>>(decb, out);
}

// Round 8
// 3174.394 us; speedup vs baseline: 1.9501x; 1.9501x over previous
//
#include <hip/hip_runtime.h>
#include <stdint.h>
#include <stddef.h>

#define TT   128
#define BB   1024
#define INN  75
#define HH   128
#define KXP  96
#define OUTN 256
#define DECN 9600
#define EPSB 1e-5f

typedef short v8s __attribute__((ext_vector_type(8)));   // 8 bf16 (4 VGPR) MFMA frag
typedef float v4f __attribute__((ext_vector_type(4)));   // 4 fp32 acc frag
typedef unsigned short ush;
typedef unsigned int   u32;
typedef unsigned long long u64;

// ---- static device workspace (fully rewritten every launch) ----
__device__ __align__(256) ush g_xpad[(size_t)TT * BB * KXP];   // x padded to K=96, [t][b][k] bf16
__device__ __align__(256) u64 g_h0s[(size_t)TT * BB * 32];     // h0 stream [t][row][128 bf16] as u64
__device__ __align__(256) u64 g_h1s[(size_t)TT * BB * 32];     // h1 stream
__device__ __align__(256) float g_c0[HH * BB];                 // c-state layer0 [unit][row] fp32
__device__ __align__(256) float g_c1[HH * BB];                 // c-state layer1
__device__ __align__(256) float g_P[(size_t)4 * 128 * 1024 * 4];   // P[stream][unit][row][gate] fp32 (8 MB)
__device__ __align__(256) float g_pst[32 * 16 * 4 * 16 * 2];   // partial stats [colgrp][r16][st][col16][S,Q]
// weights [m][k] bf16, m permuted: origcol(m) = (m&3)*128 + (m>>4)*4 + ((m>>2)&3)
__device__ __align__(256) ush g_wtih0[512 * KXP];
__device__ __align__(256) ush g_wthh0[512 * HH];
__device__ __align__(256) ush g_wtih1[512 * HH];
__device__ __align__(256) ush g_wthh1[512 * HH];
__device__ __align__(256) ush g_fcwt[OUTN * HH];               // fc_w^T [col][k]
__device__ __align__(256) ush g_decwt[(size_t)DECN * OUTN];    // dec_w^T [col][k]
__device__ __align__(256) ush g_emb[BB * OUTN];                // fc output bf16

// ---- helpers ----
__device__ __forceinline__ ush f2bf(float f) {
  u32 u = __float_as_uint(f);
  u32 r = (u + 0x7FFFu + ((u >> 16) & 1u)) >> 16;   // RNE
  return (ush)r;
}
__device__ __forceinline__ float sigf(float x)  { return 1.f / (1.f + __expf(-x)); }
__device__ __forceinline__ float tanhf_(float x){ float e = __expf(2.f * x); return 1.f - 2.f / (e + 1.f); }
__device__ __forceinline__ v8s ld8(const ush* p) { return *reinterpret_cast<const v8s*>(p); }
__device__ __forceinline__ int origcol(int m) { return (m & 3) * 128 + (m >> 4) * 4 + ((m >> 2) & 3); }

// ---- prep kernels ----
__global__ void kpackx(const float* __restrict__ seq) {
  int idx = blockIdx.x * 256 + threadIdx.x;   // < TT*BB*KXP
  int kk = idx % KXP; int rest = idx / KXP;
  int b = rest % BB;  int t = rest / BB;
  float v = (kk < INN) ? seq[((size_t)b * TT + t) * INN + kk] : 0.f;
  g_xpad[idx] = f2bf(v);
}

__global__ void kpackw(const float* __restrict__ Wih0, const float* __restrict__ Whh0,
                       const float* __restrict__ Wih1, const float* __restrict__ Whh1,
                       const float* __restrict__ fcw,  const float* __restrict__ decw) {
  int idx = blockIdx.x * 256 + threadIdx.x;   // grid 10688
  if (idx < 49152) {                          // wtih0: [m][96]
    int m = idx / KXP, k = idx % KXP;
    g_wtih0[idx] = f2bf((k < INN) ? Wih0[k * 512 + origcol(m)] : 0.f);
  } else if (idx < 114688) {
    int j = idx - 49152; int m = j / HH, k = j % HH;
    g_wthh0[j] = f2bf(Whh0[k * 512 + origcol(m)]);
  } else if (idx < 180224) {
    int j = idx - 114688; int m = j / HH, k = j % HH;
    g_wtih1[j] = f2bf(Wih1[k * 512 + origcol(m)]);
  } else if (idx < 245760) {
    int j = idx - 180224; int m = j / HH, k = j % HH;
    g_wthh1[j] = f2bf(Whh1[k * 512 + origcol(m)]);
  } else if (idx < 278528) {                  // fcwt [c][128]
    int j = idx - 245760; int c = j / HH, k = j % HH;
    g_fcwt[j] = f2bf(fcw[k * OUTN + c]);
  } else {                                    // decwt [c][256], coalesced reads
    int j = idx - 278528; int n = j % DECN, k = j / DECN;
    g_decwt[(size_t)n * OUTN + k] = f2bf(decw[(size_t)k * DECN + n]);
  }
}

// ---- kA: GEMM phase, 512 blocks x 256 thr (c = b&31 col-group, r16 = b>>5 row-slab of 64).
// Transposed MFMA (A=W^T, B=rows). Lane: row=lm, unit=c*4+lq, gates in 4 C-regs.
// Writes P[st][unit][row][gate] fp32 + per-(colgrp,r16) partial stats. No cross-block coupling.
__global__ __launch_bounds__(256, 2) void kA(int s) {
  const int tid = threadIdx.x;
  const int wv = tid >> 6, l = tid & 63;
  const int lm = l & 15, lq = l >> 4;
  const int c = blockIdx.x & 31, r16 = blockIdx.x >> 5;
  const int R0 = r16 * 64 + wv * 16;
  const int row = R0 + lm;

  __shared__ float sred[4][16][8];

  const bool aL0 = (s < TT), ah0 = (s >= 1), ah1 = (s >= 2);
  const ush* const h0r = reinterpret_cast<const ush*>(g_h0s);
  const ush* const h1r = reinterpret_cast<const ush*>(g_h1s);

  // A-frags: 16 weight cols of this group
  v8s afx[3], af0[4], af1[4], af2[4];
#pragma unroll
  for (int ks = 0; ks < 3; ++ks)
    afx[ks] = ld8(&g_wtih0[(c * 16 + lm) * KXP + ks * 32 + lq * 8]);
#pragma unroll
  for (int ks = 0; ks < 4; ++ks) {
    af0[ks] = ld8(&g_wthh0[(c * 16 + lm) * HH + ks * 32 + lq * 8]);
    af1[ks] = ld8(&g_wtih1[(c * 16 + lm) * HH + ks * 32 + lq * 8]);
    af2[ks] = ld8(&g_wthh1[(c * 16 + lm) * HH + ks * 32 + lq * 8]);
  }

  const v4f vz = {0.f, 0.f, 0.f, 0.f};
  v4f Pi0 = vz, P0 = vz, P1 = vz, P2 = vz;

  if (aL0) {
    const ush* xp = g_xpad + ((size_t)s * BB + row) * KXP + lq * 8;
#pragma unroll
    for (int ks = 0; ks < 3; ++ks)
      Pi0 = __builtin_amdgcn_mfma_f32_16x16x32_bf16(afx[ks], ld8(xp + ks * 32), Pi0, 0, 0, 0);
  }
  if (ah0) {
    const ush* hp = h0r + ((size_t)(s - 1) * BB + row) * HH + lq * 8;
#pragma unroll
    for (int ks = 0; ks < 4; ++ks) {
      v8s b = ld8(hp + ks * 32);
      P0 = __builtin_amdgcn_mfma_f32_16x16x32_bf16(af0[ks], b, P0, 0, 0, 0);
      P1 = __builtin_amdgcn_mfma_f32_16x16x32_bf16(af1[ks], b, P1, 0, 0, 0);
    }
  }
  if (ah1) {
    const ush* hp = h1r + ((size_t)(s - 2) * BB + row) * HH + lq * 8;
#pragma unroll
    for (int ks = 0; ks < 4; ++ks)
      P2 = __builtin_amdgcn_mfma_f32_16x16x32_bf16(af2[ks], ld8(hp + ks * 32), P2, 0, 0, 0);
  }

  // P stores (16B per stream per lane)
  const int unit = c * 4 + lq;
  *reinterpret_cast<v4f*>(&g_P[((size_t)(0 * 128 + unit) * 1024 + row) * 4]) = Pi0;
  *reinterpret_cast<v4f*>(&g_P[((size_t)(1 * 128 + unit) * 1024 + row) * 4]) = P0;
  *reinterpret_cast<v4f*>(&g_P[((size_t)(2 * 128 + unit) * 1024 + row) * 4]) = P1;
  *reinterpret_cast<v4f*>(&g_P[((size_t)(3 * 128 + unit) * 1024 + row) * 4]) = P2;

  // partial stats: per col, sum over this wave's 16 rows (reduce over lm lanes)
  float S[4][4], Q[4][4];
#pragma unroll
  for (int r = 0; r < 4; ++r) {
    S[0][r] = Pi0[r]; Q[0][r] = Pi0[r] * Pi0[r];
    S[1][r] = P0[r];  Q[1][r] = P0[r] * P0[r];
    S[2][r] = P1[r];  Q[2][r] = P1[r] * P1[r];
    S[3][r] = P2[r];  Q[3][r] = P2[r] * P2[r];
  }
#pragma unroll
  for (int st = 0; st < 4; ++st)
#pragma unroll
    for (int r = 0; r < 4; ++r) {
      float s_ = S[st][r], q_ = Q[st][r];
#pragma unroll
      for (int off = 1; off < 16; off <<= 1) { s_ += __shfl_xor(s_, off); q_ += __shfl_xor(q_, off); }
      S[st][r] = s_; Q[st][r] = q_;
    }
  if (lm == 0)
#pragma unroll
    for (int st = 0; st < 4; ++st)
#pragma unroll
      for (int r = 0; r < 4; ++r) {
        sred[wv][lq * 4 + r][st * 2]     = S[st][r];
        sred[wv][lq * 4 + r][st * 2 + 1] = Q[st][r];
      }
  __syncthreads();
  if (tid < 16) {
#pragma unroll
    for (int st = 0; st < 4; ++st) {
      float Sa = 0.f, Qa = 0.f;
#pragma unroll
      for (int w4 = 0; w4 < 4; ++w4) { Sa += sred[w4][tid][st * 2]; Qa += sred[w4][tid][st * 2 + 1]; }
      int base = (((c * 16 + r16) * 4 + st) * 16 + tid) * 2;
      g_pst[base] = Sa; g_pst[base + 1] = Qa;
    }
  }
}

// ---- kB: BN + pointwise + c-BN + h, 64 blocks x 512 thr.
// Block = (layer L=b>>5, unit-group g=b&31 of 4 units). Reads P slices + partial stats.
// c-stats block-local. h written as packed u64 per (row, unit-group).
__global__ __launch_bounds__(512, 2) void kB(
    int s,
    const float* __restrict__ gih0, const float* __restrict__ bih0,
    const float* __restrict__ b0,
    const float* __restrict__ ghh0, const float* __restrict__ bhh0,
    const float* __restrict__ gc0,  const float* __restrict__ bc0,
    const float* __restrict__ gih1, const float* __restrict__ bih1,
    const float* __restrict__ ghh1, const float* __restrict__ bhh1,
    const float* __restrict__ b1,   const float* __restrict__ gc1,
    const float* __restrict__ bc1) {
  const int L = blockIdx.x >> 5, g = blockIdx.x & 31;
  if (L == 0 && s >= TT) return;
  if (L == 1 && s < 1) return;

  const int tid = threadIdx.x;
  const int wv = tid >> 6, l = tid & 63;
  const int uloc = tid & 3;                 // unit within group
  const int rgrp = tid >> 2;                // 0..127, 8 rows each
  const int unit = g * 4 + uloc;

  __shared__ float scoef[16][3];            // per col: A_ih, A_hh, D
  __shared__ float scred[8][4][2];
  __shared__ float sccoef[4][2];

  // ---- reduce partial stats for this block's 16 cols, compute BN coefs ----
  if (tid < 16) {
    const int cb = tid;                     // col within group: uloc*4+gate? (cb = lq*4+r in kA) => unit=(cb>>2), gate=cb&3
    const int stb = L * 2;
    float S0 = 0.f, Q0 = 0.f, S1 = 0.f, Q1 = 0.f;
#pragma unroll
    for (int r16 = 0; r16 < 16; ++r16) {
      int b0i = (((g * 16 + r16) * 4 + stb) * 16 + cb) * 2;
      int b1i = (((g * 16 + r16) * 4 + stb + 1) * 16 + cb) * 2;
      S0 += g_pst[b0i]; Q0 += g_pst[b0i + 1];
      S1 += g_pst[b1i]; Q1 += g_pst[b1i + 1];
    }
    const int oc = origcol(g * 16 + cb);
    float mi = S0 * (1.f / BB), vi = Q0 * (1.f / BB) - mi * mi;
    float mh = S1 * (1.f / BB), vh = Q1 * (1.f / BB) - mh * mh;
    float Ai, Ah, D;
    if (L == 0) {
      Ai = gih0[oc] * rsqrtf(vi + EPSB);
      Ah = ghh0[oc] * rsqrtf(vh + EPSB);
      D = bih0[oc] - Ai * mi + bhh0[oc] - Ah * mh + b0[oc];
    } else {
      Ai = gih1[oc] * rsqrtf(vi + EPSB);
      Ah = ghh1[oc] * rsqrtf(vh + EPSB);
      D = bih1[oc] - Ai * mi + bhh1[oc] - Ah * mh + b1[oc];
    }
    scoef[cb][0] = Ai; scoef[cb][1] = Ah; scoef[cb][2] = D;
  }
  __syncthreads();

  float AI[4], AH[4], DD[4];
#pragma unroll
  for (int r = 0; r < 4; ++r) {             // cols of this unit: cb = uloc*4 + r (r = gate f,i,o,g)
    AI[r] = scoef[uloc * 4 + r][0];
    AH[r] = scoef[uloc * 4 + r][1];
    DD[r] = scoef[uloc * 4 + r][2];
  }

  // ---- pointwise over this thread's 8 rows ----
  const int stb = L * 2;
  const float* Pih = &g_P[(size_t)((stb * 128 + unit) * 1024) * 4];
  const float* Phh = &g_P[(size_t)(((stb + 1) * 128 + unit) * 1024) * 4];
  float* cptr = (L == 0) ? &g_c0[unit * BB] : &g_c1[unit * BB];
  const bool cold0 = (L == 0) ? (s == 0) : (s == 1);

  float cst[8], so[8];
  float cS = 0.f, cQ = 0.f;
#pragma unroll
  for (int i = 0; i < 8; ++i) {
    const int row = rgrp * 8 + i;
    v4f pih = *reinterpret_cast<const v4f*>(&Pih[row * 4]);
    v4f phh = *reinterpret_cast<const v4f*>(&Phh[row * 4]);
    float gf = AI[0] * pih[0] + AH[0] * phh[0] + DD[0];
    float gi = AI[1] * pih[1] + AH[1] * phh[1] + DD[1];
    float go = AI[2] * pih[2] + AH[2] * phh[2] + DD[2];
    float gg = AI[3] * pih[3] + AH[3] * phh[3] + DD[3];
    float cold = cold0 ? 0.f : cptr[row];
    float c1 = sigf(gf) * cold + sigf(gi) * tanhf_(gg);
    cst[i] = c1; so[i] = sigf(go);
    cptr[row] = c1;
    cS += c1; cQ += c1 * c1;
  }

  // ---- c-BN stats: reduce over lanes sharing uloc, then across waves ----
#pragma unroll
  for (int off = 4; off < 64; off <<= 1) { cS += __shfl_xor(cS, off); cQ += __shfl_xor(cQ, off); }
  if (l < 4) { scred[wv][l][0] = cS; scred[wv][l][1] = cQ; }
  __syncthreads();
  if (tid < 4) {
    float S = 0.f, Q = 0.f;
#pragma unroll
    for (int w8 = 0; w8 < 8; ++w8) { S += scred[w8][tid][0]; Q += scred[w8][tid][1]; }
    float m_ = S * (1.f / BB), v_ = Q * (1.f / BB) - m_ * m_;
    int uu = g * 4 + tid;
    float gcv = (L == 0) ? gc0[uu] : gc1[uu];
    float bcv = (L == 0) ? bc0[uu] : bc1[uu];
    float ac = gcv * rsqrtf(v_ + EPSB);
    sccoef[tid][0] = ac; sccoef[tid][1] = bcv - ac * m_;
  }
  __syncthreads();
  const float ac = sccoef[uloc][0], dc = sccoef[uloc][1];

  // ---- h output: pack 4 units (shfl) -> u64 store per row ----
  u64* hdst = (L == 0) ? &g_h0s[(size_t)s * BB * 32] : &g_h1s[(size_t)(s - 1) * BB * 32];
#pragma unroll
  for (int i = 0; i < 8; ++i) {
    const int row = rgrp * 8 + i;
    u32 v = (u32)f2bf(so[i] * tanhf_(ac * cst[i] + dc));
    u32 a = v | (__shfl_xor(v, 1) << 16);   // valid on even uloc
    u32 b = __shfl_xor(a, 2);               // uloc0 <- (u2,u3)
    if (uloc == 0) hdst[(size_t)row * 32 + g] = (u64)a | ((u64)b << 32);
  }
}

// ---- epilogue: emb = h1(T-1) @ fc_w + fc_b (bf16 out) ----
__global__ __launch_bounds__(256) void kfc(const float* __restrict__ fcb) {
  const int tid = threadIdx.x, w = tid >> 6, l = tid & 63;
  const int lm = l & 15, lq = l >> 4;
  const int col = blockIdx.x * 16 + lm;   // grid 16
  const ush* hsrc = reinterpret_cast<const ush*>(g_h1s) + (size_t)(TT - 1) * BB * HH;
  v8s bf[4];
#pragma unroll
  for (int ks = 0; ks < 4; ++ks) bf[ks] = ld8(&g_fcwt[col * HH + ks * 32 + lq * 8]);
  const float bias = fcb[col];
  const v4f vz = {0.f, 0.f, 0.f, 0.f};
#pragma unroll
  for (int mt = 0; mt < 16; ++mt) {
    const int rowa = w * 256 + mt * 16 + lm;
    const ush* ap = hsrc + (size_t)rowa * HH + lq * 8;
    v4f acc = vz;
#pragma unroll
    for (int ks = 0; ks < 4; ++ks)
      acc = __builtin_amdgcn_mfma_f32_16x16x32_bf16(ld8(ap + ks * 32), bf[ks], acc, 0, 0, 0);
#pragma unroll
    for (int r = 0; r < 4; ++r) {
      int row = w * 256 + mt * 16 + lq * 4 + r;
      g_emb[row * OUTN + col] = f2bf(acc[r] + bias);
    }
  }
}

// ---- epilogue: out = emb @ dec_w + dec_b, transposed MFMA -> 16B coalesced stores ----
__global__ __launch_bounds__(256) void kdec(const float* __restrict__ decb, float* __restrict__ out) {
  const int tid = threadIdx.x, wv = tid >> 6, l = tid & 63;
  const int lm = l & 15, lq = l >> 4;
  const int c0 = blockIdx.x * 16;         // grid 600
  const int R0 = wv * 256;
  v8s af[8];
#pragma unroll
  for (int ks = 0; ks < 8; ++ks) af[ks] = ld8(&g_decwt[(size_t)(c0 + lm) * OUTN + ks * 32 + lq * 8]);
  float bias[4];
#pragma unroll
  for (int r = 0; r < 4; ++r) bias[r] = decb[c0 + lq * 4 + r];
  const v4f vz = {0.f, 0.f, 0.f, 0.f};
#pragma unroll
  for (int mt = 0; mt < 16; ++mt) {
    const int row = R0 + mt * 16 + lm;
    const ush* bp = g_emb + (size_t)row * OUTN + lq * 8;
    v4f acc = vz;
#pragma unroll
    for (int ks = 0; ks < 8; ++ks)
      acc = __builtin_amdgcn_mfma_f32_16x16x32_bf16(af[ks], ld8(bp + ks * 32), acc, 0, 0, 0);
    v4f o;
#pragma unroll
    for (int r = 0; r < 4; ++r) o[r] = acc[r] + bias[r];
    *reinterpret_cast<v4f*>(&out[(size_t)row * DECN + c0 + lq * 4]) = o;
  }
}

extern "C" void kernel_launch(void* const* d_in, const int* in_sizes, int n_in,
                              void* d_out, int out_size, void* d_ws, size_t ws_size,
                              hipStream_t stream) {
  const float* seq  = (const float*)d_in[0];
  const float* Wih0 = (const float*)d_in[1];
  const float* Whh0 = (const float*)d_in[2];
  const float* b0   = (const float*)d_in[3];
  const float* gih0 = (const float*)d_in[4];
  const float* bih0 = (const float*)d_in[5];
  const float* ghh0 = (const float*)d_in[6];
  const float* bhh0 = (const float*)d_in[7];
  const float* gc0  = (const float*)d_in[8];
  const float* bc0  = (const float*)d_in[9];
  const float* Wih1 = (const float*)d_in[10];
  const float* Whh1 = (const float*)d_in[11];
  const float* b1   = (const float*)d_in[12];
  const float* gih1 = (const float*)d_in[13];
  const float* bih1 = (const float*)d_in[14];
  const float* ghh1 = (const float*)d_in[15];
  const float* bhh1 = (const float*)d_in[16];
  const float* gc1  = (const float*)d_in[17];
  const float* bc1  = (const float*)d_in[18];
  const float* fcw  = (const float*)d_in[19];
  const float* fcb  = (const float*)d_in[20];
  const float* decw = (const float*)d_in[21];
  const float* decb = (const float*)d_in[22];
  float* out = (float*)d_out;
  (void)in_sizes; (void)n_in; (void)out_size; (void)d_ws; (void)ws_size;

  kpackx<<<dim3((TT * BB * KXP) / 256), dim3(256), 0, stream>>>(seq);
  kpackw<<<dim3(10688), dim3(256), 0, stream>>>(Wih0, Whh0, Wih1, Whh1, fcw, decw);
  for (int s = 0; s <= TT; ++s) {
    kA<<<dim3(512), dim3(256), 0, stream>>>(s);
    kB<<<dim3(64), dim3(512), 0, stream>>>(s, gih0, bih0, b0, ghh0, bhh0, gc0, bc0,
                                           gih1, bih1, ghh1, bhh1, b1, gc1, bc1);
  }
  kfc<<<dim3(16), dim3(256), 0, stream>>>(fcb);
  kdec<<<dim3(600), dim3(256), 0, stream>>>(decb, out);
}

// Round 9
// 2721.897 us; speedup vs baseline: 2.2743x; 1.1662x over previous
//
#include <hip/hip_runtime.h>
#include <stdint.h>
#include <stddef.h>

#define TT   128
#define BB   1024
#define INN  75
#define HH   128
#define KXP  96
#define OUTN 256
#define DECN 9600
#define EPSB 1e-5f

typedef short v8s __attribute__((ext_vector_type(8)));   // 8 bf16 (4 VGPR) MFMA frag
typedef float v4f __attribute__((ext_vector_type(4)));   // 4 fp32 acc frag
typedef unsigned short ush;
typedef unsigned int   u32;
typedef unsigned long long u64;

// ---- static device workspace (fully rewritten every launch) ----
__device__ __align__(256) ush g_xpad[(size_t)TT * BB * KXP];   // x padded to K=96, [t][b][k] bf16
__device__ __align__(256) u64 g_G1[(size_t)TT * 32 * BB * 4];  // BN(x@Wih0)+b0, [t][g][row][16 bf16] (134 MB)
__device__ __align__(256) u64 g_h0s[(size_t)TT * BB * 32];     // h0 stream [t][row][128 bf16] as u64
__device__ __align__(256) u64 g_h1s[(size_t)TT * BB * 32];     // h1 stream
__device__ __align__(256) float g_c[(size_t)2 * 32 * BB * 4];  // c-state [L][g][row][4 units] fp32
__device__ __align__(256) float g_P[(size_t)3 * 32 * BB * 16]; // P[st][g][row][16] fp32 (6 MB), st: hh0,ih1,hh1
__device__ __align__(256) float g_pst[32 * 16 * 3 * 16 * 2];   // partial stats [c][r16][st][col16][S,Q]
// weights [m][k] bf16, m permuted: origcol(m) = (m&3)*128 + (m>>4)*4 + ((m>>2)&3)
__device__ __align__(256) ush g_wtih0[512 * KXP];
__device__ __align__(256) ush g_wthh0[512 * HH];
__device__ __align__(256) ush g_wtih1[512 * HH];
__device__ __align__(256) ush g_wthh1[512 * HH];
__device__ __align__(256) ush g_fcwt[OUTN * HH];               // fc_w^T [col][k]
__device__ __align__(256) ush g_decwt[(size_t)DECN * OUTN];    // dec_w^T [col][k]
__device__ __align__(256) ush g_emb[BB * OUTN];                // fc output bf16

// ---- helpers ----
__device__ __forceinline__ ush f2bf(float f) {
  u32 u = __float_as_uint(f);
  u32 r = (u + 0x7FFFu + ((u >> 16) & 1u)) >> 16;   // RNE
  return (ush)r;
}
__device__ __forceinline__ float bf2f(ush u) { return __uint_as_float(((u32)u) << 16); }
__device__ __forceinline__ float sigf(float x)  { return 1.f / (1.f + __expf(-x)); }
__device__ __forceinline__ float tanhf_(float x){ float e = __expf(2.f * x); return 1.f - 2.f / (e + 1.f); }
__device__ __forceinline__ v8s ld8(const ush* p) { return *reinterpret_cast<const v8s*>(p); }
__device__ __forceinline__ int origcol(int m) { return (m & 3) * 128 + (m >> 4) * 4 + ((m >> 2) & 3); }

// ---- prep kernels ----
__global__ void kpackx(const float* __restrict__ seq) {
  int idx = blockIdx.x * 256 + threadIdx.x;   // < TT*BB*KXP
  int kk = idx % KXP; int rest = idx / KXP;
  int b = rest % BB;  int t = rest / BB;
  float v = (kk < INN) ? seq[((size_t)b * TT + t) * INN + kk] : 0.f;
  g_xpad[idx] = f2bf(v);
}

__global__ void kpackw(const float* __restrict__ Wih0, const float* __restrict__ Whh0,
                       const float* __restrict__ Wih1, const float* __restrict__ Whh1,
                       const float* __restrict__ fcw,  const float* __restrict__ decw) {
  int idx = blockIdx.x * 256 + threadIdx.x;   // grid 10688
  if (idx < 49152) {                          // wtih0: [m][96]
    int m = idx / KXP, k = idx % KXP;
    g_wtih0[idx] = f2bf((k < INN) ? Wih0[k * 512 + origcol(m)] : 0.f);
  } else if (idx < 114688) {
    int j = idx - 49152; int m = j / HH, k = j % HH;
    g_wthh0[j] = f2bf(Whh0[k * 512 + origcol(m)]);
  } else if (idx < 180224) {
    int j = idx - 114688; int m = j / HH, k = j % HH;
    g_wtih1[j] = f2bf(Wih1[k * 512 + origcol(m)]);
  } else if (idx < 245760) {
    int j = idx - 180224; int m = j / HH, k = j % HH;
    g_wthh1[j] = f2bf(Whh1[k * 512 + origcol(m)]);
  } else if (idx < 278528) {                  // fcwt [c][128]
    int j = idx - 245760; int c = j / HH, k = j % HH;
    g_fcwt[j] = f2bf(fcw[k * OUTN + c]);
  } else {                                    // decwt [c][256], coalesced reads
    int j = idx - 278528; int n = j % DECN, k = j / DECN;
    g_decwt[(size_t)n * OUTN + k] = f2bf(decw[(size_t)k * DECN + n]);
  }
}

// G1[t][g][row][16] = BN_ih0(x_t @ Wih0) + b0 (folded), transposed-MFMA orientation.
// grid TT*8 (t, ct): block covers 64 m-cols (4 tiles of 16), 8 waves split the 1024 rows.
__global__ __launch_bounds__(512) void kprep(const float* __restrict__ gih0,
                                             const float* __restrict__ bih0,
                                             const float* __restrict__ b0) {
  const int t = blockIdx.x >> 3, ct = blockIdx.x & 7;
  const int tid = threadIdx.x, wv = tid >> 6, l = tid & 63;
  const int lm = l & 15, lq = l >> 4;
  const int R0 = wv * 128;
  __shared__ float sred[8][64][2];
  __shared__ float scoef[64][2];

  v8s af[4][3];
#pragma unroll
  for (int tt = 0; tt < 4; ++tt)
#pragma unroll
    for (int ks = 0; ks < 3; ++ks)
      af[tt][ks] = ld8(&g_wtih0[(ct * 64 + tt * 16 + lm) * KXP + ks * 32 + lq * 8]);

  const v4f vz = {0.f, 0.f, 0.f, 0.f};
  v4f acc[8][4];
#pragma unroll
  for (int mt = 0; mt < 8; ++mt)
#pragma unroll
    for (int tt = 0; tt < 4; ++tt) acc[mt][tt] = vz;

#pragma unroll
  for (int mt = 0; mt < 8; ++mt) {
    const ush* xr = g_xpad + ((size_t)t * BB + R0 + mt * 16 + lm) * KXP + lq * 8;
    v8s bx0 = ld8(xr), bx1 = ld8(xr + 32), bx2 = ld8(xr + 64);
#pragma unroll
    for (int tt = 0; tt < 4; ++tt) {
      acc[mt][tt] = __builtin_amdgcn_mfma_f32_16x16x32_bf16(af[tt][0], bx0, acc[mt][tt], 0, 0, 0);
      acc[mt][tt] = __builtin_amdgcn_mfma_f32_16x16x32_bf16(af[tt][1], bx1, acc[mt][tt], 0, 0, 0);
      acc[mt][tt] = __builtin_amdgcn_mfma_f32_16x16x32_bf16(af[tt][2], bx2, acc[mt][tt], 0, 0, 0);
    }
  }
  // stats per m-col
  float S[4][4], Q[4][4];
#pragma unroll
  for (int tt = 0; tt < 4; ++tt)
#pragma unroll
    for (int r = 0; r < 4; ++r) {
      float s = 0.f, q = 0.f;
#pragma unroll
      for (int mt = 0; mt < 8; ++mt) { float a = acc[mt][tt][r]; s += a; q += a * a; }
#pragma unroll
      for (int off = 1; off < 16; off <<= 1) { s += __shfl_xor(s, off); q += __shfl_xor(q, off); }
      S[tt][r] = s; Q[tt][r] = q;
    }
  if (lm == 0)
#pragma unroll
    for (int tt = 0; tt < 4; ++tt)
#pragma unroll
      for (int r = 0; r < 4; ++r) {
        sred[wv][tt * 16 + lq * 4 + r][0] = S[tt][r];
        sred[wv][tt * 16 + lq * 4 + r][1] = Q[tt][r];
      }
  __syncthreads();
  if (tid < 64) {
    float Sa = 0.f, Qa = 0.f;
#pragma unroll
    for (int w8 = 0; w8 < 8; ++w8) { Sa += sred[w8][tid][0]; Qa += sred[w8][tid][1]; }
    int oc = origcol(ct * 64 + tid);
    float m_ = Sa * (1.f / BB), v_ = Qa * (1.f / BB) - m_ * m_;
    float A = gih0[oc] * rsqrtf(v_ + EPSB);
    scoef[tid][0] = A; scoef[tid][1] = bih0[oc] - A * m_ + b0[oc];
  }
  __syncthreads();
  float CA[4][4], CD[4][4];
#pragma unroll
  for (int tt = 0; tt < 4; ++tt)
#pragma unroll
    for (int r = 0; r < 4; ++r) {
      CA[tt][r] = scoef[tt * 16 + lq * 4 + r][0];
      CD[tt][r] = scoef[tt * 16 + lq * 4 + r][1];
    }
#pragma unroll
  for (int mt = 0; mt < 8; ++mt) {
    const int row = R0 + mt * 16 + lm;
#pragma unroll
    for (int tt = 0; tt < 4; ++tt) {
      const int g = ct * 4 + tt;
      u32 lo = (u32)f2bf(CA[tt][0] * acc[mt][tt][0] + CD[tt][0])
             | ((u32)f2bf(CA[tt][1] * acc[mt][tt][1] + CD[tt][1]) << 16);
      u32 hi = (u32)f2bf(CA[tt][2] * acc[mt][tt][2] + CD[tt][2])
             | ((u32)f2bf(CA[tt][3] * acc[mt][tt][3] + CD[tt][3]) << 16);
      g_G1[(((size_t)t * 32 + g) * BB + row) * 4 + lq] = (u64)lo | ((u64)hi << 32);
    }
  }
}

// ---- kA: GEMM phase, 512 blocks x 256 thr (c = b&31 col-group, r16 = b>>5 row-slab of 64).
// Transposed MFMA (A=W^T, B=rows). Lane: row=lm, m = lq*4+r -> unit c*4+lq, gate r.
// 3 streams: 0=hh0, 1=ih1, 2=hh1. P[st][c][row][16] fp32, wave stores 1KB contiguous.
__global__ __launch_bounds__(256, 2) void kA(int s) {
  const int tid = threadIdx.x;
  const int wv = tid >> 6, l = tid & 63;
  const int lm = l & 15, lq = l >> 4;
  const int c = blockIdx.x & 31, r16 = blockIdx.x >> 5;
  const int row = r16 * 64 + wv * 16 + lm;

  __shared__ float sred[4][16][6];

  const bool h0ok = (s >= 1), h1ok = (s >= 2);
  const ush* const h0r = reinterpret_cast<const ush*>(g_h0s);
  const ush* const h1r = reinterpret_cast<const ush*>(g_h1s);

  v8s af0[4], af1[4], af2[4];
#pragma unroll
  for (int ks = 0; ks < 4; ++ks) {
    af0[ks] = ld8(&g_wthh0[(c * 16 + lm) * HH + ks * 32 + lq * 8]);
    af1[ks] = ld8(&g_wtih1[(c * 16 + lm) * HH + ks * 32 + lq * 8]);
    af2[ks] = ld8(&g_wthh1[(c * 16 + lm) * HH + ks * 32 + lq * 8]);
  }

  const v4f vz = {0.f, 0.f, 0.f, 0.f};
  v4f P0 = vz, P1 = vz, P2 = vz;

  if (h0ok) {
    const ush* hp = h0r + ((size_t)(s - 1) * BB + row) * HH + lq * 8;
#pragma unroll
    for (int ks = 0; ks < 4; ++ks) {
      v8s b = ld8(hp + ks * 32);
      P0 = __builtin_amdgcn_mfma_f32_16x16x32_bf16(af0[ks], b, P0, 0, 0, 0);
      P1 = __builtin_amdgcn_mfma_f32_16x16x32_bf16(af1[ks], b, P1, 0, 0, 0);
    }
  }
  if (h1ok) {
    const ush* hp = h1r + ((size_t)(s - 2) * BB + row) * HH + lq * 8;
#pragma unroll
    for (int ks = 0; ks < 4; ++ks)
      P2 = __builtin_amdgcn_mfma_f32_16x16x32_bf16(af2[ks], ld8(hp + ks * 32), P2, 0, 0, 0);
  }

  // P stores: [st][c][row][16], lane offset lq*4 -> wave = 16 rows x 64B contiguous
  if (s < TT)
    *reinterpret_cast<v4f*>(&g_P[(((size_t)0 * 32 + c) * BB + row) * 16 + lq * 4]) = P0;
  if (s >= 1) {
    *reinterpret_cast<v4f*>(&g_P[(((size_t)1 * 32 + c) * BB + row) * 16 + lq * 4]) = P1;
    *reinterpret_cast<v4f*>(&g_P[(((size_t)2 * 32 + c) * BB + row) * 16 + lq * 4]) = P2;
  }

  // partial stats: per col, sum over this wave's 16 rows (reduce over lm lanes)
  float S[3][4], Q[3][4];
#pragma unroll
  for (int r = 0; r < 4; ++r) {
    S[0][r] = P0[r]; Q[0][r] = P0[r] * P0[r];
    S[1][r] = P1[r]; Q[1][r] = P1[r] * P1[r];
    S[2][r] = P2[r]; Q[2][r] = P2[r] * P2[r];
  }
#pragma unroll
  for (int st = 0; st < 3; ++st)
#pragma unroll
    for (int r = 0; r < 4; ++r) {
      float s_ = S[st][r], q_ = Q[st][r];
#pragma unroll
      for (int off = 1; off < 16; off <<= 1) { s_ += __shfl_xor(s_, off); q_ += __shfl_xor(q_, off); }
      S[st][r] = s_; Q[st][r] = q_;
    }
  if (lm == 0)
#pragma unroll
    for (int st = 0; st < 3; ++st)
#pragma unroll
      for (int r = 0; r < 4; ++r) {
        sred[wv][lq * 4 + r][st * 2]     = S[st][r];
        sred[wv][lq * 4 + r][st * 2 + 1] = Q[st][r];
      }
  __syncthreads();
  if (tid < 16) {
#pragma unroll
    for (int st = 0; st < 3; ++st) {
      float Sa = 0.f, Qa = 0.f;
#pragma unroll
      for (int w4 = 0; w4 < 4; ++w4) { Sa += sred[w4][tid][st * 2]; Qa += sred[w4][tid][st * 2 + 1]; }
      int base = (((c * 16 + r16) * 3 + st) * 16 + tid) * 2;
      g_pst[base] = Sa; g_pst[base + 1] = Qa;
    }
  }
}

// ---- kB: BN + pointwise + c-BN + h, 64 blocks x 512 thr.
// Block = (layer L=b>>5, unit-group g=b&31). Coalesced P/G1 reads (4 thr = 64B, rows consecutive).
__global__ __launch_bounds__(512, 2) void kB(
    int s,
    const float* __restrict__ ghh0, const float* __restrict__ bhh0,
    const float* __restrict__ gc0,  const float* __restrict__ bc0,
    const float* __restrict__ gih1, const float* __restrict__ bih1,
    const float* __restrict__ ghh1, const float* __restrict__ bhh1,
    const float* __restrict__ b1,   const float* __restrict__ gc1,
    const float* __restrict__ bc1) {
  const int L = blockIdx.x >> 5, g = blockIdx.x & 31;
  if (L == 0 && s >= TT) return;
  if (L == 1 && s < 1) return;

  const int tid = threadIdx.x;
  const int wv = tid >> 6, l = tid & 63;
  const int uloc = tid & 3;                 // unit within group
  const int rgrp = tid >> 2;                // 0..127, 8 rows each

  __shared__ float scoef[16][3];            // per col: L0 {Ah,D}, L1 {Ai,Ah,D}
  __shared__ float scred[8][4][2];
  __shared__ float sccoef[4][2];

  // ---- reduce partial stats, compute BN coefs ----
  if (tid < 16) {
    const int cb = tid;                     // col in group: unit=cb>>2, gate=cb&3
    const int oc = origcol(g * 16 + cb);
    if (L == 0) {
      float S = 0.f, Q = 0.f;
#pragma unroll
      for (int r16 = 0; r16 < 16; ++r16) {
        int bi = (((g * 16 + r16) * 3 + 0) * 16 + cb) * 2;
        S += g_pst[bi]; Q += g_pst[bi + 1];
      }
      float m_ = S * (1.f / BB), v_ = Q * (1.f / BB) - m_ * m_;
      float Ah = ghh0[oc] * rsqrtf(v_ + EPSB);
      scoef[cb][0] = Ah; scoef[cb][1] = bhh0[oc] - Ah * m_;
    } else {
      float S1 = 0.f, Q1 = 0.f, S2 = 0.f, Q2 = 0.f;
#pragma unroll
      for (int r16 = 0; r16 < 16; ++r16) {
        int b1i = (((g * 16 + r16) * 3 + 1) * 16 + cb) * 2;
        int b2i = (((g * 16 + r16) * 3 + 2) * 16 + cb) * 2;
        S1 += g_pst[b1i]; Q1 += g_pst[b1i + 1];
        S2 += g_pst[b2i]; Q2 += g_pst[b2i + 1];
      }
      float m1 = S1 * (1.f / BB), v1 = Q1 * (1.f / BB) - m1 * m1;
      float Ai = gih1[oc] * rsqrtf(v1 + EPSB);
      float m2 = S2 * (1.f / BB), v2 = Q2 * (1.f / BB) - m2 * m2;
      float Ah = ghh1[oc] * rsqrtf(v2 + EPSB);
      scoef[cb][0] = Ai; scoef[cb][1] = Ah;
      scoef[cb][2] = bih1[oc] - Ai * m1 + bhh1[oc] - Ah * m2 + b1[oc];
    }
  }
  __syncthreads();

  float C0[4], C1[4], C2[4];
#pragma unroll
  for (int r = 0; r < 4; ++r) {
    C0[r] = scoef[uloc * 4 + r][0];
    C1[r] = scoef[uloc * 4 + r][1];
    C2[r] = scoef[uloc * 4 + r][2];
  }

  // ---- pointwise over this thread's 8 rows ----
  float* cptr = &g_c[((size_t)(L * 32 + g) * BB) * 4];
  const bool cold0 = (L == 0) ? (s == 0) : (s == 1);
  const float* Pa = &g_P[(((size_t)(L == 0 ? 0 : 1) * 32 + g) * BB) * 16];
  const float* Pb = &g_P[(((size_t)2 * 32 + g) * BB) * 16];   // only used for L1
  const u64*   G1p = &g_G1[(((size_t)s * 32 + g) * BB) * 4];  // only used for L0

  float cst[8], so[8];
  float cS = 0.f, cQ = 0.f;
#pragma unroll
  for (int i = 0; i < 8; ++i) {
    const int row = rgrp * 8 + i;
    float gf, gi, go, gg;
    v4f pa = *reinterpret_cast<const v4f*>(&Pa[row * 16 + uloc * 4]);
    if (L == 0) {
      u64 g1 = G1p[row * 4 + uloc];
      gf = bf2f((ush)g1)         + C0[0] * pa[0] + C1[0];
      gi = bf2f((ush)(g1 >> 16)) + C0[1] * pa[1] + C1[1];
      go = bf2f((ush)(g1 >> 32)) + C0[2] * pa[2] + C1[2];
      gg = bf2f((ush)(g1 >> 48)) + C0[3] * pa[3] + C1[3];
    } else {
      v4f pb = *reinterpret_cast<const v4f*>(&Pb[row * 16 + uloc * 4]);
      gf = C0[0] * pa[0] + C1[0] * pb[0] + C2[0];
      gi = C0[1] * pa[1] + C1[1] * pb[1] + C2[1];
      go = C0[2] * pa[2] + C1[2] * pb[2] + C2[2];
      gg = C0[3] * pa[3] + C1[3] * pb[3] + C2[3];
    }
    float cold = cold0 ? 0.f : cptr[row * 4 + uloc];
    float c1 = sigf(gf) * cold + sigf(gi) * tanhf_(gg);
    cst[i] = c1; so[i] = sigf(go);
    cptr[row * 4 + uloc] = c1;
    cS += c1; cQ += c1 * c1;
  }

  // ---- c-BN stats ----
#pragma unroll
  for (int off = 4; off < 64; off <<= 1) { cS += __shfl_xor(cS, off); cQ += __shfl_xor(cQ, off); }
  if (l < 4) { scred[wv][l][0] = cS; scred[wv][l][1] = cQ; }
  __syncthreads();
  if (tid < 4) {
    float S = 0.f, Q = 0.f;
#pragma unroll
    for (int w8 = 0; w8 < 8; ++w8) { S += scred[w8][tid][0]; Q += scred[w8][tid][1]; }
    float m_ = S * (1.f / BB), v_ = Q * (1.f / BB) - m_ * m_;
    int uu = g * 4 + tid;
    float gcv = (L == 0) ? gc0[uu] : gc1[uu];
    float bcv = (L == 0) ? bc0[uu] : bc1[uu];
    float ac = gcv * rsqrtf(v_ + EPSB);
    sccoef[tid][0] = ac; sccoef[tid][1] = bcv - ac * m_;
  }
  __syncthreads();
  const float ac = sccoef[uloc][0], dc = sccoef[uloc][1];

  // ---- h output: pack 4 units (shfl) -> u64 store per row ----
  u64* hdst = (L == 0) ? &g_h0s[(size_t)s * BB * 32] : &g_h1s[(size_t)(s - 1) * BB * 32];
#pragma unroll
  for (int i = 0; i < 8; ++i) {
    const int row = rgrp * 8 + i;
    u32 v = (u32)f2bf(so[i] * tanhf_(ac * cst[i] + dc));
    u32 a = v | (__shfl_xor(v, 1) << 16);   // valid on even uloc
    u32 b = __shfl_xor(a, 2);               // uloc0 <- (u2,u3)
    if (uloc == 0) hdst[(size_t)row * 32 + g] = (u64)a | ((u64)b << 32);
  }
}

// ---- epilogue: emb = h1(T-1) @ fc_w + fc_b (bf16 out) ----
__global__ __launch_bounds__(256) void kfc(const float* __restrict__ fcb) {
  const int tid = threadIdx.x, w = tid >> 6, l = tid & 63;
  const int lm = l & 15, lq = l >> 4;
  const int col = blockIdx.x * 16 + lm;   // grid 16
  const ush* hsrc = reinterpret_cast<const ush*>(g_h1s) + (size_t)(TT - 1) * BB * HH;
  v8s bf[4];
#pragma unroll
  for (int ks = 0; ks < 4; ++ks) bf[ks] = ld8(&g_fcwt[col * HH + ks * 32 + lq * 8]);
  const float bias = fcb[col];
  const v4f vz = {0.f, 0.f, 0.f, 0.f};
#pragma unroll
  for (int mt = 0; mt < 16; ++mt) {
    const int rowa = w * 256 + mt * 16 + lm;
    const ush* ap = hsrc + (size_t)rowa * HH + lq * 8;
    v4f acc = vz;
#pragma unroll
    for (int ks = 0; ks < 4; ++ks)
      acc = __builtin_amdgcn_mfma_f32_16x16x32_bf16(ld8(ap + ks * 32), bf[ks], acc, 0, 0, 0);
#pragma unroll
    for (int r = 0; r < 4; ++r) {
      int row = w * 256 + mt * 16 + lq * 4 + r;
      g_emb[row * OUTN + col] = f2bf(acc[r] + bias);
    }
  }
}

// ---- epilogue: out = emb @ dec_w + dec_b, transposed MFMA -> 16B coalesced stores ----
__global__ __launch_bounds__(256) void kdec(const float* __restrict__ decb, float* __restrict__ out) {
  const int tid = threadIdx.x, wv = tid >> 6, l = tid & 63;
  const int lm = l & 15, lq = l >> 4;
  const int c0 = blockIdx.x * 16;         // grid 600
  const int R0 = wv * 256;
  v8s af[8];
#pragma unroll
  for (int ks = 0; ks < 8; ++ks) af[ks] = ld8(&g_decwt[(size_t)(c0 + lm) * OUTN + ks * 32 + lq * 8]);
  float bias[4];
#pragma unroll
  for (int r = 0; r < 4; ++r) bias[r] = decb[c0 + lq * 4 + r];
  const v4f vz = {0.f, 0.f, 0.f, 0.f};
#pragma unroll
  for (int mt = 0; mt < 16; ++mt) {
    const int row = R0 + mt * 16 + lm;
    const ush* bp = g_emb + (size_t)row * OUTN + lq * 8;
    v4f acc = vz;
#pragma unroll
    for (int ks = 0; ks < 8; ++ks)
      acc = __builtin_amdgcn_mfma_f32_16x16x32_bf16(af[ks], ld8(bp + ks * 32), acc, 0, 0, 0);
    v4f o;
#pragma unroll
    for (int r = 0; r < 4; ++r) o[r] = acc[r] + bias[r];
    *reinterpret_cast<v4f*>(&out[(size_t)row * DECN + c0 + lq * 4]) = o;
  }
}

extern "C" void kernel_launch(void* const* d_in, const int* in_sizes, int n_in,
                              void* d_out, int out_size, void* d_ws, size_t ws_size,
                              hipStream_t stream) {
  const float* seq  = (const float*)d_in[0];
  const float* Wih0 = (const float*)d_in[1];
  const float* Whh0 = (const float*)d_in[2];
  const float* b0   = (const float*)d_in[3];
  const float* gih0 = (const float*)d_in[4];
  const float* bih0 = (const float*)d_in[5];
  const float* ghh0 = (const float*)d_in[6];
  const float* bhh0 = (const float*)d_in[7];
  const float* gc0  = (const float*)d_in[8];
  const float* bc0  = (const float*)d_in[9];
  const float* Wih1 = (const float*)d_in[10];
  const float* Whh1 = (const float*)d_in[11];
  const float* b1   = (const float*)d_in[12];
  const float* gih1 = (const float*)d_in[13];
  const float* bih1 = (const float*)d_in[14];
  const float* ghh1 = (const float*)d_in[15];
  const float* bhh1 = (const float*)d_in[16];
  const float* gc1  = (const float*)d_in[17];
  const float* bc1  = (const float*)d_in[18];
  const float* fcw  = (const float*)d_in[19];
  const float* fcb  = (const float*)d_in[20];
  const float* decw = (const float*)d_in[21];
  const float* decb = (const float*)d_in[22];
  float* out = (float*)d_out;
  (void)in_sizes; (void)n_in; (void)out_size; (void)d_ws; (void)ws_size;

  kpackx<<<dim3((TT * BB * KXP) / 256), dim3(256), 0, stream>>>(seq);
  kpackw<<<dim3(10688), dim3(256), 0, stream>>>(Wih0, Whh0, Wih1, Whh1, fcw, decw);
  kprep<<<dim3(TT * 8), dim3(512), 0, stream>>>(gih0, bih0, b0);
  for (int s = 0; s <= TT; ++s) {
    kA<<<dim3(512), dim3(256), 0, stream>>>(s);
    kB<<<dim3(64), dim3(512), 0, stream>>>(s, ghh0, bhh0, gc0, bc0,
                                           gih1, bih1, ghh1, bhh1, b1, gc1, bc1);
  }
  kfc<<<dim3(16), dim3(256), 0, stream>>>(fcb);
  kdec<<<dim3(600), dim3(256), 0, stream>>>(decb, out);
}